// Round 1
// baseline (890.329 us; speedup 1.0000x reference)
//
#include <hip/hip_runtime.h>
#include <hip/hip_bf16.h>

#define NN 50000
#define NR 8
#define DIM 128
#define NE 800000
#define TM 32     // targets per block
#define CAP 1024  // per-block bucket capacity (mean 512, Poisson -> overflow prob ~0; guarded)
#define NB 1563   // ceil(NN/TM)
#define CPAD 132  // f32 accum row stride (128 + 4): 16B-aligned rows, stride==4 mod 32 banks

using floatx4 = __attribute__((ext_vector_type(4))) float;
using bf16x8  = __attribute__((ext_vector_type(8))) __bf16;

// ---------------- workspace layout (in floats) ----------------
// zeroed region: [0, 826160) = cnt + wsum + S2X1 + blkcnt
#define OFF_CNT   0u         // 400000: int counts, seg = t*8+r
#define OFF_WSUM  400000u    // 400000: wsum[r*NN+h] fp32 atomic accum
#define OFF_S2    800000u    // 1152: S2[1024] + X1[128]
#define OFF_BCNT  801152u    // 1563*16 ints: per-block bucket counters (64B stride)
#define OFF_BBUF  826160u    // 1563*1024 ints: per-block edge buckets, pk = (j2<<17)|head
#define OFF_XB    2426672u   // 6.4M bf16: x_emb in bf16 (16B aligned)
#define OFF_WF    5626672u   // 9*2048*8 bf16: weights in MFMA frag order
#define OFF_S2P   5700400u   // NB*1152: per-block S2/X1 partials
// total 7,500,976 floats = 30.0 MB

// ---------------- merged prep: bf16 cast + weight frags + cnt atomics + bucket assign ----------------
// KEY CHANGE vs prior round: bucket key is TERM-MAJOR  j2 = (r<<5)|(t&31)  so each
// term's edges form a contiguous CSR range inside the block (enables edge-parallel sweep).
__global__ __launch_bounds__(256) void prep_k(
    const float* __restrict__ x, __bf16* __restrict__ xb,
    const float* __restrict__ W1, const float* __restrict__ root1, __bf16* __restrict__ wf,
    const int* __restrict__ h, const int* __restrict__ r, const int* __restrict__ t,
    int* __restrict__ cnt, int* __restrict__ blkcnt, int* __restrict__ blkbuf)
{
    const int gid = blockIdx.x * 256 + threadIdx.x;
    const int nthr = gridDim.x * 256;

    if (gid < 9 * 2048) {
        int mat = gid >> 11, idx = gid & 2047;
        const float* B = (mat < 8) ? (W1 + (size_t)mat * DIM * DIM) : root1;
        int lt = idx & 63, fid = idx >> 6;
        int s = fid >> 3, nt = fid & 7;
        int n = nt * 16 + (lt & 15);
        int kb = s * 32 + (lt >> 4) * 8;
        bf16x8 v;
#pragma unroll
        for (int j = 0; j < 8; ++j) v[j] = (__bf16)B[(kb + j) * DIM + n];
        *reinterpret_cast<bf16x8*>(wf + ((size_t)mat * 2048 + idx) * 8) = v;
    }
    for (int i = gid; i < NN * DIM / 4; i += nthr) {
        int base = i * 4;
        float4 v = *reinterpret_cast<const float4*>(x + base);
        __bf16 o[4] = {(__bf16)v.x, (__bf16)v.y, (__bf16)v.z, (__bf16)v.w};
        *reinterpret_cast<uint2*>(xb + base) = *reinterpret_cast<uint2*>(o);
    }
    // edge loop: cnt atomic + bucket append (shares the h/r/t loads)
    for (int i = gid; i < NE / 4; i += nthr) {
        int base = i * 4;
        int4 hv = *reinterpret_cast<const int4*>(h + base);
        int4 rv = *reinterpret_cast<const int4*>(r + base);
        int4 tv = *reinterpret_cast<const int4*>(t + base);
#pragma unroll
        for (int j = 0; j < 4; ++j) {
            int te = (j == 0) ? tv.x : (j == 1) ? tv.y : (j == 2) ? tv.z : tv.w;
            int re = (j == 0) ? rv.x : (j == 1) ? rv.y : (j == 2) ? rv.z : rv.w;
            int he = (j == 0) ? hv.x : (j == 1) ? hv.y : (j == 2) ? hv.z : hv.w;
            atomicAdd(&cnt[te * NR + re], 1);
            int blk = te >> 5;
            int pos = atomicAdd(&blkcnt[blk * 16], 1);
            if (pos < CAP) blkbuf[blk * CAP + pos] = (((re << 5) | (te & 31)) << 17) | he;
        }
    }
}

// ---------------- wsum: 800k fire-and-forget float atomics; inv derived from cnt (no scan!) ----------------
__global__ void wsum_k(const int* __restrict__ h, const int* __restrict__ r, const int* __restrict__ t,
                       const int* __restrict__ cnt, float* __restrict__ wsum) {
    int base = (blockIdx.x * 256 + threadIdx.x) * 4;
    if (base + 3 < NE) {
        int4 hv = *reinterpret_cast<const int4*>(h + base);
        int4 rv = *reinterpret_cast<const int4*>(r + base);
        int4 tv = *reinterpret_cast<const int4*>(t + base);
        int c0 = cnt[tv.x * NR + rv.x], c1 = cnt[tv.y * NR + rv.y];
        int c2 = cnt[tv.z * NR + rv.z], c3 = cnt[tv.w * NR + rv.w];
        atomicAdd(&wsum[rv.x * NN + hv.x], 1.0f / (float)(c0 > 1 ? c0 : 1));
        atomicAdd(&wsum[rv.y * NN + hv.y], 1.0f / (float)(c1 > 1 ? c1 : 1));
        atomicAdd(&wsum[rv.z * NN + hv.z], 1.0f / (float)(c2 > 1 ? c2 : 1));
        atomicAdd(&wsum[rv.w * NN + hv.w], 1.0f / (float)(c3 > 1 ? c3 : 1));
    } else {
        for (int e = base; e < NE; ++e) {
            int c = cnt[t[e] * NR + r[e]];
            atomicAdd(&wsum[r[e] * NN + h[e]], 1.0f / (float)(c > 1 ? c : 1));
        }
    }
}

// ---------------- fused layer 1 + layer-2 partials: local CSR + EDGE-PARALLEL ds_add accumulate ----------------
// Old: per-thread segment walk (chains of mean length 2 -> ~0.16 loads in flight/wave, latency-bound).
// New: per term-pair, edges are a contiguous CSR range; 16 slots x 16 lanes sweep the list in
// double-buffered chunks of 64 edges (8 load-instrs in flight/wave) and ds_add_f32 each edge's
// 128-f32 row into a zeroed LDS accum tile [64][CPAD]. MFMA A-frags read f32 accum * invl -> bf16.
// Chunk-0 of tp+1 is prefetched before tp's MFMA so the barrier's vmcnt(0) drain hides fill latency.
__global__ __launch_bounds__(256, 3) void rgcn_fused_k(
    const int* __restrict__ blkcnt, const int* __restrict__ blkbuf,
    const __bf16* __restrict__ xb, const __bf16* __restrict__ wf,
    const float* __restrict__ b1, const float* __restrict__ wsum,
    float* __restrict__ S2P)
{
    __shared__ __attribute__((aligned(16))) float accum[64 * CPAD];  // 33.0 KB (also scan temp + red scratch)
    __shared__ int   loffs[TM * NR + 1];
    __shared__ int   lcnt[TM * NR];
    __shared__ int   cursor[TM * NR];
    __shared__ float invl[TM * NR];
    __shared__ float wsl[NR][TM];
    __shared__ int   pkd[CAP];          // full pk = (j2<<17)|head, sorted by j2 (term-major)
    const int tid = threadIdx.x;
    const int wave = tid >> 6, lane = tid & 63, quad = lane >> 4;
    const int slot = tid >> 4, sl = tid & 15;   // 16 edge slots x 16 lanes (8 cols each)
    const int tbase = blockIdx.x * TM;

    // ---- local CSR build (j2 = term*32 + trow) ----
    int n = blkcnt[blockIdx.x * 16];
    if (n > CAP) n = CAP;
    const int* gbuf = blkbuf + (size_t)blockIdx.x * CAP;
    lcnt[tid] = 0;
    __syncthreads();
    int pk0 = -1, pk1 = -1, pk2 = -1, pk3 = -1;
    if (tid < n)       { pk0 = gbuf[tid];       atomicAdd(&lcnt[pk0 >> 17], 1); }
    if (tid + 256 < n) { pk1 = gbuf[tid + 256]; atomicAdd(&lcnt[pk1 >> 17], 1); }
    if (tid + 512 < n) { pk2 = gbuf[tid + 512]; atomicAdd(&lcnt[pk2 >> 17], 1); }
    if (tid + 768 < n) { pk3 = gbuf[tid + 768]; atomicAdd(&lcnt[pk3 >> 17], 1); }
    __syncthreads();
    int v = lcnt[tid];
    int* ss = reinterpret_cast<int*>(accum);
    ss[tid] = v;
    __syncthreads();
#pragma unroll
    for (int off = 1; off < 256; off <<= 1) {
        int val = (tid >= off) ? ss[tid - off] : 0;
        __syncthreads();
        if (tid >= off) ss[tid] += val;
        __syncthreads();
    }
    loffs[tid + 1] = ss[tid];            // inclusive
    if (tid == 0) loffs[0] = 0;
    cursor[tid] = ss[tid] - v;           // exclusive
    invl[tid] = 1.0f / (float)(v > 1 ? v : 1);
    {
        int rr = tid >> 5, nn = tbase + (tid & 31);
        wsl[rr][tid & 31] = (nn < NN) ? wsum[rr * NN + nn] : 0.f;
    }
    __syncthreads();
    if (pk0 >= 0) { int p = atomicAdd(&cursor[pk0 >> 17], 1); pkd[p] = pk0; }
    if (pk1 >= 0) { int p = atomicAdd(&cursor[pk1 >> 17], 1); pkd[p] = pk1; }
    if (pk2 >= 0) { int p = atomicAdd(&cursor[pk2 >> 17], 1); pkd[p] = pk2; }
    if (pk3 >= 0) { int p = atomicAdd(&cursor[pk3 >> 17], 1); pkd[p] = pk3; }
    __syncthreads();

    floatx4 C[4];
#pragma unroll
    for (int i = 0; i < 4; ++i) C[i] = (floatx4)0.f;
    const int arow = (wave & 1) * 16 + (lane & 15);   // wave row-strip
    const int ntg0 = (wave >> 1) * 4;                 // wave col-strip (4 nt each)

    // issue load for chunk-iteration ii of range [AA, AA+mm); rowa = accum row or -1
    auto LOADQ = [&](int AA, int mm, int base_tp, int ii, bf16x8 &y, int &rowa) {
        int idx = ii * 16 + slot;
        rowa = -1;
        if (idx < mm) {
            int pk = pkd[AA + idx];                    // slot-uniform -> LDS broadcast
            rowa = (pk >> 17) - (base_tp << 6);        // 0..63
            y = *reinterpret_cast<const bf16x8*>(xb + (size_t)(pk & 0x1FFFF) * DIM + (sl << 3));
        }
    };
    // ds_add_f32 the edge row into accum (f32). ~4-way bank alias inherent (8-col/lane), accepted.
    auto ACCQ = [&](const bf16x8 &y, int rowa) {
        if (rowa >= 0) {
            float* d = accum + rowa * CPAD + (sl << 3);
#pragma unroll
            for (int k = 0; k < 8; ++k) atomicAdd(d + k, (float)y[k]);
        }
    };

    // prefetch chunk 0 of tp 0 (pkd is ready; accum not needed yet)
    int A_ = loffs[0];
    int m_ = loffs[64] - A_;
    bf16x8 ya0, ya1, ya2, ya3; int ra0, ra1, ra2, ra3;
    LOADQ(A_, m_, 0, 0, ya0, ra0);
    LOADQ(A_, m_, 0, 1, ya1, ra1);
    LOADQ(A_, m_, 0, 2, ya2, ra2);
    LOADQ(A_, m_, 0, 3, ya3, ra3);

    for (int tp = 0; tp < 4; ++tp) {
        // zero accum tile (prefetched loads fill under this + the barrier drain)
        {
            floatx4* az = reinterpret_cast<floatx4*>(accum);
            for (int j = tid; j < (64 * CPAD) / 4; j += 256) az[j] = (floatx4)0.f;
        }
        __syncthreads();

        const int P = (m_ + 15) >> 4;
        {
            bf16x8 yb0, yb1, yb2, yb3; int rb0, rb1, rb2, rb3;
            int i = 0;
            for (; i + 4 < P; i += 4) {
                LOADQ(A_, m_, tp, i + 4, yb0, rb0);
                LOADQ(A_, m_, tp, i + 5, yb1, rb1);
                LOADQ(A_, m_, tp, i + 6, yb2, rb2);
                LOADQ(A_, m_, tp, i + 7, yb3, rb3);
                ACCQ(ya0, ra0); ACCQ(ya1, ra1); ACCQ(ya2, ra2); ACCQ(ya3, ra3);
                ya0 = yb0; ra0 = rb0; ya1 = yb1; ra1 = rb1;
                ya2 = yb2; ra2 = rb2; ya3 = yb3; ra3 = rb3;
            }
            ACCQ(ya0, ra0); ACCQ(ya1, ra1); ACCQ(ya2, ra2); ACCQ(ya3, ra3);
        }
        __syncthreads();

        // prefetch chunk 0 of next tp: fills during the MFMA phase, drained at the trailing barrier
        if (tp < 3) {
            A_ = loffs[(tp + 1) * 64];
            m_ = loffs[(tp + 1) * 64 + 64] - A_;
            LOADQ(A_, m_, tp + 1, 0, ya0, ra0);
            LOADQ(A_, m_, tp + 1, 1, ya1, ra1);
            LOADQ(A_, m_, tp + 1, 2, ya2, ra2);
            LOADQ(A_, m_, tp + 1, 3, ya3, ra3);
        }

        // ---- MFMA both terms of the pair: af = bf16(accum * invl) read straight from f32 tile ----
#pragma unroll
        for (int u = 0; u < 2; ++u) {
            const __bf16* wterm = wf + (size_t)(tp * 2 + u) * 2048 * 8;
            float sinv = invl[(tp * 2 + u) * 32 + arow];
#pragma unroll
            for (int s = 0; s < 4; ++s) {
                const float* ap = accum + (u * 32 + arow) * CPAD + s * 32 + quad * 8;
                floatx4 f0 = *reinterpret_cast<const floatx4*>(ap);
                floatx4 f1 = *reinterpret_cast<const floatx4*>(ap + 4);
                bf16x8 af;
#pragma unroll
                for (int k = 0; k < 4; ++k) {
                    af[k]     = (__bf16)(f0[k] * sinv);
                    af[k + 4] = (__bf16)(f1[k] * sinv);
                }
#pragma unroll
                for (int nt = 0; nt < 4; ++nt) {
                    bf16x8 bfv = *reinterpret_cast<const bf16x8*>(
                        wterm + (size_t)((s * 8 + ntg0 + nt) * 64 + lane) * 8);
                    C[nt] = __builtin_amdgcn_mfma_f32_16x16x32_bf16(af, bfv, C[nt], 0, 0, 0);
                }
            }
        }
        __syncthreads();
    }

    // ---- root term: af rows read directly from global xb (no LDS staging) ----
    {
        const __bf16* wterm = wf + (size_t)8 * 2048 * 8;
        int node = tbase + arow;
#pragma unroll
        for (int s = 0; s < 4; ++s) {
            bf16x8 af;
            if (node < NN) {
                af = *reinterpret_cast<const bf16x8*>(xb + (size_t)node * DIM + s * 32 + quad * 8);
            } else {
#pragma unroll
                for (int j = 0; j < 8; ++j) af[j] = (__bf16)0.f;
            }
#pragma unroll
            for (int nt = 0; nt < 4; ++nt) {
                bf16x8 bfv = *reinterpret_cast<const bf16x8*>(
                    wterm + (size_t)((s * 8 + ntg0 + nt) * 64 + lane) * 8);
                C[nt] = __builtin_amdgcn_mfma_f32_16x16x32_bf16(af, bfv, C[nt], 0, 0, 0);
            }
        }
    }

    // ---- epilogue: bias + relu in-register, fused S2/X1 block partials (accum dead -> red scratch) ----
    float* red = accum;   // [4][576] = 9.2 KB
    const int rowl0 = (wave & 1) * 16 + quad * 4;
    const int colc = lane & 15;
#pragma unroll
    for (int nt = 0; nt < 4; ++nt) {
        float badd = b1[ntg0 * 16 + nt * 16 + colc];
#pragma unroll
        for (int i = 0; i < 4; ++i) C[nt][i] = fmaxf(C[nt][i] + badd, 0.f);
    }
    float rmask[4];
#pragma unroll
    for (int i = 0; i < 4; ++i) rmask[i] = (tbase + rowl0 + i < NN) ? 1.f : 0.f;
#pragma unroll
    for (int nt = 0; nt < 4; ++nt) {
        float p = rmask[0] * C[nt][0] + rmask[1] * C[nt][1] + rmask[2] * C[nt][2] + rmask[3] * C[nt][3];
        p += __shfl_xor(p, 16);
        p += __shfl_xor(p, 32);
        if (quad == 0) red[wave * 576 + nt * 16 + colc] = p;
    }
#pragma unroll
    for (int rr = 0; rr < NR; ++rr) {
        float w0 = wsl[rr][rowl0], w1 = wsl[rr][rowl0 + 1];
        float w2 = wsl[rr][rowl0 + 2], w3 = wsl[rr][rowl0 + 3];
#pragma unroll
        for (int nt = 0; nt < 4; ++nt) {
            float p = w0 * C[nt][0] + w1 * C[nt][1] + w2 * C[nt][2] + w3 * C[nt][3];
            p += __shfl_xor(p, 16);
            p += __shfl_xor(p, 32);
            if (quad == 0) red[wave * 576 + 64 + rr * 64 + nt * 16 + colc] = p;
        }
    }
    __syncthreads();
    for (int j = tid; j < 1152; j += 256) {
        int rr = j >> 7, c = j & 127;          // rr==8 -> X1
        int u = c >> 6, cc = c & 63;
        int o = (rr < 8) ? (64 + rr * 64 + cc) : cc;
        S2P[(size_t)blockIdx.x * 1152 + j] = red[(u * 2) * 576 + o] + red[(u * 2 + 1) * 576 + o];
    }
}

// ---------------- reduce S2P[NB][1152] -> S2X1[1152] (atomic finish, 63 stripes of 25) ----------------
// Old grid of 40 blocks was latency-bound (196 strided loads/thread on 10k threads). 315 blocks.
__global__ void s2red_k(const float* __restrict__ S2P, float* __restrict__ S2X1) {
    int cb = blockIdx.x % 5, stripe = blockIdx.x / 5;
    int c = cb * 256 + threadIdx.x;
    if (c >= 1152) return;
    int b0 = stripe * 25, b1 = min(NB, b0 + 25);
    float s0 = 0.f, s1 = 0.f;
    int b = b0;
    for (; b + 1 < b1; b += 2) {
        s0 += S2P[(size_t)b * 1152 + c];
        s1 += S2P[(size_t)(b + 1) * 1152 + c];
    }
    if (b < b1) s0 += S2P[(size_t)b * 1152 + c];
    atomicAdd(&S2X1[c], s0 + s1);
}

// ---------------- final: out = (S2.W2 + X1.root2)/N + b2  (1024 thr, 8-way split, 2 ILP chains) ----------------
__global__ __launch_bounds__(1024) void final_k(
    const float* __restrict__ S2X1, const float* __restrict__ W2,
    const float* __restrict__ root2, const float* __restrict__ b2, float* __restrict__ out)
{
    __shared__ float red[1024];
    const int o = threadIdx.x & 127, c = threadIdx.x >> 7;  // 8 chunks of 144 terms
    float s = 0.f, s2 = 0.f;
#pragma unroll 2
    for (int j = c * 144; j < (c + 1) * 144; j += 2) {
        float v0 = S2X1[j], v1 = S2X1[j + 1];
        float w0 = (j < 1024) ? W2[(size_t)j * DIM + o] : root2[(size_t)(j - 1024) * DIM + o];
        float w1 = (j + 1 < 1024) ? W2[(size_t)(j + 1) * DIM + o] : root2[(size_t)(j + 1 - 1024) * DIM + o];
        s += v0 * w0; s2 += v1 * w1;
    }
    red[threadIdx.x] = s + s2;
    __syncthreads();
    if (c == 0) {
        float tot = 0.f;
#pragma unroll
        for (int k = 0; k < 8; ++k) tot += red[o + 128 * k];
        out[o] = tot * (1.0f / NN) + b2[o];
    }
}

extern "C" void kernel_launch(void* const* d_in, const int* in_sizes, int n_in,
                              void* d_out, int out_size, void* d_ws, size_t ws_size,
                              hipStream_t stream)
{
    const int*   h     = (const int*)d_in[0];
    const int*   r     = (const int*)d_in[1];
    const int*   t     = (const int*)d_in[2];
    const float* x_emb = (const float*)d_in[3];
    const float* W1    = (const float*)d_in[4];
    const float* root1 = (const float*)d_in[5];
    const float* b1    = (const float*)d_in[6];
    const float* W2    = (const float*)d_in[7];
    const float* root2 = (const float*)d_in[8];
    const float* b2    = (const float*)d_in[9];

    float* ws     = (float*)d_ws;
    int*   cnt    = (int*)(ws + OFF_CNT);
    float* wsum   = ws + OFF_WSUM;
    float* S2     = ws + OFF_S2;      // 1024 S2 + 128 X1 contiguous
    int*   blkcnt = (int*)(ws + OFF_BCNT);
    int*   blkbuf = (int*)(ws + OFF_BBUF);
    __bf16* xb    = (__bf16*)(ws + OFF_XB);
    __bf16* wf    = (__bf16*)(ws + OFF_WF);
    float* S2P    = ws + OFF_S2P;

    // zero cnt + wsum + S2X1 + blkcnt (ws re-poisoned to 0xAA before every timed launch)
    hipMemsetAsync(ws, 0, (size_t)826160 * sizeof(float), stream);

    // merged cast + weight-frag + count + bucket-assign (one edge pass, term-major key)
    prep_k<<<1600, 256, 0, stream>>>(x_emb, xb, W1, root1, wf, h, r, t, cnt, blkcnt, blkbuf);

    // wsum: inv derived from cnt directly (no scan, no CSR)
    wsum_k<<<782, 256, 0, stream>>>(h, r, t, cnt, wsum);

    // fused layer 1 + layer-2 partials: local CSR + edge-parallel ds_add accumulate
    rgcn_fused_k<<<NB, 256, 0, stream>>>(blkcnt, blkbuf, xb, wf, b1, wsum, S2P);

    s2red_k<<<315, 256, 0, stream>>>(S2P, S2);
    final_k<<<1, 1024, 0, stream>>>(S2, W2, root2, b2, (float*)d_out);
}

// Round 2
// 341.000 us; speedup vs baseline: 2.6109x; 2.6109x over previous
//
#include <hip/hip_runtime.h>
#include <hip/hip_bf16.h>

#define NN 50000
#define NR 8
#define DIM 128
#define NE 800000
#define TM 32     // targets per block
#define CAP 1024  // per-block bucket capacity (mean 512, Poisson -> overflow prob ~0; guarded)
#define NB 1563   // ceil(NN/TM)
#define SPAD 136  // staging/Atile row stride in bf16 (272B: 16B-aligned rows, stride/4 == 4 mod 32 banks)

using floatx4 = __attribute__((ext_vector_type(4))) float;
using bf16x8  = __attribute__((ext_vector_type(8))) __bf16;

// ---------------- workspace layout (in floats) ----------------
// zeroed region: [0, 826160) = cnt + wsum + S2X1 + blkcnt
#define OFF_CNT   0u         // 400000: int counts, seg = t*8+r
#define OFF_WSUM  400000u    // 400000: wsum[r*NN+h] fp32 atomic accum
#define OFF_S2    800000u    // 1152: S2[1024] + X1[128]
#define OFF_BCNT  801152u    // 1563*16 ints: per-block bucket counters (64B stride)
#define OFF_BBUF  826160u    // 1563*1024 ints: per-block edge buckets, pk = (j2<<17)|head
#define OFF_XB    2426672u   // 6.4M bf16: x_emb in bf16 (16B aligned)
#define OFF_WF    5626672u   // 9*2048*8 bf16: weights in MFMA frag order
#define OFF_S2P   5700400u   // NB*1152: per-block S2/X1 partials
// total 7,500,976 floats = 30.0 MB

// ---------------- merged prep: bf16 cast + weight frags + cnt atomics + bucket assign ----------------
// bucket key TERM-MAJOR j2 = (r<<5)|(t&31): each term-pair's edges form ONE contiguous CSR
// range inside the block -> enables chunked edge-parallel staging in the fused kernel.
__global__ __launch_bounds__(256) void prep_k(
    const float* __restrict__ x, __bf16* __restrict__ xb,
    const float* __restrict__ W1, const float* __restrict__ root1, __bf16* __restrict__ wf,
    const int* __restrict__ h, const int* __restrict__ r, const int* __restrict__ t,
    int* __restrict__ cnt, int* __restrict__ blkcnt, int* __restrict__ blkbuf)
{
    const int gid = blockIdx.x * 256 + threadIdx.x;
    const int nthr = gridDim.x * 256;

    if (gid < 9 * 2048) {
        int mat = gid >> 11, idx = gid & 2047;
        const float* B = (mat < 8) ? (W1 + (size_t)mat * DIM * DIM) : root1;
        int lt = idx & 63, fid = idx >> 6;
        int s = fid >> 3, nt = fid & 7;
        int n = nt * 16 + (lt & 15);
        int kb = s * 32 + (lt >> 4) * 8;
        bf16x8 v;
#pragma unroll
        for (int j = 0; j < 8; ++j) v[j] = (__bf16)B[(kb + j) * DIM + n];
        *reinterpret_cast<bf16x8*>(wf + ((size_t)mat * 2048 + idx) * 8) = v;
    }
    for (int i = gid; i < NN * DIM / 4; i += nthr) {
        int base = i * 4;
        float4 v = *reinterpret_cast<const float4*>(x + base);
        __bf16 o[4] = {(__bf16)v.x, (__bf16)v.y, (__bf16)v.z, (__bf16)v.w};
        *reinterpret_cast<uint2*>(xb + base) = *reinterpret_cast<uint2*>(o);
    }
    // edge loop: cnt atomic + bucket append (shares the h/r/t loads)
    for (int i = gid; i < NE / 4; i += nthr) {
        int base = i * 4;
        int4 hv = *reinterpret_cast<const int4*>(h + base);
        int4 rv = *reinterpret_cast<const int4*>(r + base);
        int4 tv = *reinterpret_cast<const int4*>(t + base);
#pragma unroll
        for (int j = 0; j < 4; ++j) {
            int te = (j == 0) ? tv.x : (j == 1) ? tv.y : (j == 2) ? tv.z : tv.w;
            int re = (j == 0) ? rv.x : (j == 1) ? rv.y : (j == 2) ? rv.z : rv.w;
            int he = (j == 0) ? hv.x : (j == 1) ? hv.y : (j == 2) ? hv.z : hv.w;
            atomicAdd(&cnt[te * NR + re], 1);
            int blk = te >> 5;
            int pos = atomicAdd(&blkcnt[blk * 16], 1);
            if (pos < CAP) blkbuf[blk * CAP + pos] = (((re << 5) | (te & 31)) << 17) | he;
        }
    }
}

// ---------------- wsum: 800k fire-and-forget float atomics; inv derived from cnt (no scan!) ----------------
__global__ void wsum_k(const int* __restrict__ h, const int* __restrict__ r, const int* __restrict__ t,
                       const int* __restrict__ cnt, float* __restrict__ wsum) {
    int base = (blockIdx.x * 256 + threadIdx.x) * 4;
    if (base + 3 < NE) {
        int4 hv = *reinterpret_cast<const int4*>(h + base);
        int4 rv = *reinterpret_cast<const int4*>(r + base);
        int4 tv = *reinterpret_cast<const int4*>(t + base);
        int c0 = cnt[tv.x * NR + rv.x], c1 = cnt[tv.y * NR + rv.y];
        int c2 = cnt[tv.z * NR + rv.z], c3 = cnt[tv.w * NR + rv.w];
        atomicAdd(&wsum[rv.x * NN + hv.x], 1.0f / (float)(c0 > 1 ? c0 : 1));
        atomicAdd(&wsum[rv.y * NN + hv.y], 1.0f / (float)(c1 > 1 ? c1 : 1));
        atomicAdd(&wsum[rv.z * NN + hv.z], 1.0f / (float)(c2 > 1 ? c2 : 1));
        atomicAdd(&wsum[rv.w * NN + hv.w], 1.0f / (float)(c3 > 1 ? c3 : 1));
    } else {
        for (int e = base; e < NE; ++e) {
            int c = cnt[t[e] * NR + r[e]];
            atomicAdd(&wsum[r[e] * NN + h[e]], 1.0f / (float)(c > 1 ? c : 1));
        }
    }
}

// ---------------- fused layer 1 + layer-2 partials: stage-then-reduce (ZERO atomics in hot path) ----------------
// Per term-pair tp (contiguous edge range in pkd):
//   chunk loop (64 edges): regs -> ds_write staging (plain writes) ; next chunk's global loads
//   issued immediately after (one full reduce-phase of latency hiding) ; barrier ;
//   segmented reduce from staging: thread (lrt = row-term 0..63, qw = wave = 32-col quarter)
//   sums its CSR range into 32 f32 regs. No atomics, no same-address serialization.
// One 17.4 KB LDS buffer time-shares: scan scratch -> staging -> Atile -> epilogue scratch.
__global__ __launch_bounds__(256, 4) void rgcn_fused_k(
    const int* __restrict__ blkcnt, const int* __restrict__ blkbuf,
    const __bf16* __restrict__ xb, const __bf16* __restrict__ wf,
    const float* __restrict__ b1, const float* __restrict__ wsum,
    float* __restrict__ S2P)
{
    __shared__ __attribute__((aligned(16))) __bf16 buf[64 * SPAD];  // 17.4 KB, time-shared
    __shared__ int   loffs[TM * NR + 1];
    __shared__ int   lcnt[TM * NR];
    __shared__ int   cursor[TM * NR];
    __shared__ float invl[TM * NR];
    __shared__ float wsl[NR][TM];
    __shared__ int   pkd[CAP];          // heads, sorted by j2 (term-major)
    const int tid = threadIdx.x;
    const int wave = tid >> 6, lane = tid & 63, quad = lane >> 4;
    const int slot = tid >> 4, sl = tid & 15;   // 16 loader slots x 16 lanes (8 cols each)
    const int lrt = tid & 63, qw = tid >> 6;    // reducer: row-term 0..63, col quarter 0..3
    const int tbase = blockIdx.x * TM;

    // ---- local CSR build (j2 = term*32 + trow) ----
    int n = blkcnt[blockIdx.x * 16];
    if (n > CAP) n = CAP;
    const int* gbuf = blkbuf + (size_t)blockIdx.x * CAP;
    lcnt[tid] = 0;
    __syncthreads();
    int pk0 = -1, pk1 = -1, pk2 = -1, pk3 = -1;
    if (tid < n)       { pk0 = gbuf[tid];       atomicAdd(&lcnt[pk0 >> 17], 1); }
    if (tid + 256 < n) { pk1 = gbuf[tid + 256]; atomicAdd(&lcnt[pk1 >> 17], 1); }
    if (tid + 512 < n) { pk2 = gbuf[tid + 512]; atomicAdd(&lcnt[pk2 >> 17], 1); }
    if (tid + 768 < n) { pk3 = gbuf[tid + 768]; atomicAdd(&lcnt[pk3 >> 17], 1); }
    __syncthreads();
    int v = lcnt[tid];
    int* ss = reinterpret_cast<int*>(buf);
    ss[tid] = v;
    __syncthreads();
#pragma unroll
    for (int off = 1; off < 256; off <<= 1) {
        int val = (tid >= off) ? ss[tid - off] : 0;
        __syncthreads();
        if (tid >= off) ss[tid] += val;
        __syncthreads();
    }
    loffs[tid + 1] = ss[tid];            // inclusive
    if (tid == 0) loffs[0] = 0;
    cursor[tid] = ss[tid] - v;           // exclusive
    invl[tid] = 1.0f / (float)(v > 1 ? v : 1);
    {
        int rr = tid >> 5, nn = tbase + (tid & 31);
        wsl[rr][tid & 31] = (nn < NN) ? wsum[rr * NN + nn] : 0.f;
    }
    __syncthreads();
    if (pk0 >= 0) { int p = atomicAdd(&cursor[pk0 >> 17], 1); pkd[p] = pk0 & 0x1FFFF; }
    if (pk1 >= 0) { int p = atomicAdd(&cursor[pk1 >> 17], 1); pkd[p] = pk1 & 0x1FFFF; }
    if (pk2 >= 0) { int p = atomicAdd(&cursor[pk2 >> 17], 1); pkd[p] = pk2 & 0x1FFFF; }
    if (pk3 >= 0) { int p = atomicAdd(&cursor[pk3 >> 17], 1); pkd[p] = pk3 & 0x1FFFF; }
    __syncthreads();

    floatx4 C[4];
#pragma unroll
    for (int i = 0; i < 4; ++i) C[i] = (floatx4)0.f;
    const int arow = (wave & 1) * 16 + (lane & 15);   // MFMA wave row-strip
    const int ntg0 = (wave >> 1) * 4;                 // MFMA wave col-strip (4 nt each)

    // 64-edge chunk staging: loads (coalesced 256B/edge-row, fully independent) and plain writes
    bf16x8 st[4];
    auto LOADCHUNK = [&](int base, int end) {
#pragma unroll
        for (int i = 0; i < 4; ++i) {
            int pos = base + slot + 16 * i;
            if (pos < end) {
                int he = pkd[pos];                    // slot-uniform -> LDS broadcast
                st[i] = *reinterpret_cast<const bf16x8*>(xb + (size_t)he * DIM + sl * 8);
            }
        }
    };
    auto WRITECHUNK = [&](int base, int end) {
#pragma unroll
        for (int i = 0; i < 4; ++i) {
            int pos = base + slot + 16 * i;
            if (pos < end)
                *reinterpret_cast<bf16x8*>(&buf[(slot + 16 * i) * SPAD + sl * 8]) = st[i];
        }
    };

    // prologue: prefetch chunk 0 of tp 0 (pkd ready; buf free after scan)
    LOADCHUNK(loffs[0], loffs[64]);

    for (int tp = 0; tp < 4; ++tp) {
        const int tpS = loffs[tp * 64], tpE = loffs[tp * 64 + 64];
        const int m = tpE - tpS, NC = (m + 63) >> 6;
        const int s0g = loffs[tp * 64 + lrt], s1g = loffs[tp * 64 + lrt + 1];
        float acc[32];
#pragma unroll
        for (int k = 0; k < 32; ++k) acc[k] = 0.f;

        if (NC == 0) {
            if (tp < 3) LOADCHUNK(loffs[(tp + 1) * 64], loffs[(tp + 1) * 64 + 64]);
        } else {
            for (int c = 0; c < NC; ++c) {
                int Cb = tpS + c * 64;
                WRITECHUNK(Cb, tpE);                      // consumes st (WAR on regs is free)
                if (c + 1 < NC)      LOADCHUNK(Cb + 64, tpE);
                else if (tp < 3)     LOADCHUNK(loffs[(tp + 1) * 64], loffs[(tp + 1) * 64 + 64]);
                __syncthreads();                          // staging visible
                int lo = s0g - Cb; lo = lo < 0 ? 0 : lo;
                int hi = s1g - Cb; hi = hi > 64 ? 64 : hi;
                for (int e = lo; e < hi; ++e) {
                    const __bf16* p = buf + e * SPAD + qw * 32;
#pragma unroll
                    for (int j = 0; j < 4; ++j) {
                        bf16x8 yv = *reinterpret_cast<const bf16x8*>(p + j * 8);
#pragma unroll
                        for (int k = 0; k < 8; ++k) acc[j * 8 + k] += (float)yv[k];
                    }
                }
                __syncthreads();                          // staging reusable
            }
        }

        // ---- accum -> Atile (scale by 1/cnt, cvt to bf16); Atile row = lrt = u*32 + trow ----
        {
            float sinv = invl[tp * 64 + lrt];
#pragma unroll
            for (int j = 0; j < 4; ++j) {
                bf16x8 o;
#pragma unroll
                for (int k = 0; k < 8; ++k) o[k] = (__bf16)(acc[j * 8 + k] * sinv);
                *reinterpret_cast<bf16x8*>(&buf[lrt * SPAD + qw * 32 + j * 8]) = o;
            }
        }
        __syncthreads();

        // ---- MFMA both terms of the pair (R0-proven pattern; Atile stride SPAD) ----
#pragma unroll
        for (int u = 0; u < 2; ++u) {
            const __bf16* wterm = wf + (size_t)(tp * 2 + u) * 2048 * 8;
#pragma unroll
            for (int s = 0; s < 4; ++s) {
                bf16x8 af = *reinterpret_cast<const bf16x8*>(
                    &buf[(u * 32 + arow) * SPAD + s * 32 + quad * 8]);
#pragma unroll
                for (int nt = 0; nt < 4; ++nt) {
                    bf16x8 bfv = *reinterpret_cast<const bf16x8*>(
                        wterm + (size_t)((s * 8 + ntg0 + nt) * 64 + lane) * 8);
                    C[nt] = __builtin_amdgcn_mfma_f32_16x16x32_bf16(af, bfv, C[nt], 0, 0, 0);
                }
            }
        }
        __syncthreads();                                  // Atile free -> staging next tp
    }

    // ---- root term: af rows read directly from global xb (no LDS staging) ----
    {
        const __bf16* wterm = wf + (size_t)8 * 2048 * 8;
        int node = tbase + arow;
#pragma unroll
        for (int s = 0; s < 4; ++s) {
            bf16x8 af;
            if (node < NN) {
                af = *reinterpret_cast<const bf16x8*>(xb + (size_t)node * DIM + s * 32 + quad * 8);
            } else {
#pragma unroll
                for (int j = 0; j < 8; ++j) af[j] = (__bf16)0.f;
            }
#pragma unroll
            for (int nt = 0; nt < 4; ++nt) {
                bf16x8 bfv = *reinterpret_cast<const bf16x8*>(
                    wterm + (size_t)((s * 8 + ntg0 + nt) * 64 + lane) * 8);
                C[nt] = __builtin_amdgcn_mfma_f32_16x16x32_bf16(af, bfv, C[nt], 0, 0, 0);
            }
        }
    }

    // ---- epilogue: bias + relu in-register, fused S2/X1 block partials (buf dead -> red scratch) ----
    float* red = reinterpret_cast<float*>(buf);   // [4][576] = 9.2 KB <= 17.4 KB
    const int rowl0 = (wave & 1) * 16 + quad * 4;
    const int colc = lane & 15;
#pragma unroll
    for (int nt = 0; nt < 4; ++nt) {
        float badd = b1[ntg0 * 16 + nt * 16 + colc];
#pragma unroll
        for (int i = 0; i < 4; ++i) C[nt][i] = fmaxf(C[nt][i] + badd, 0.f);
    }
    float rmask[4];
#pragma unroll
    for (int i = 0; i < 4; ++i) rmask[i] = (tbase + rowl0 + i < NN) ? 1.f : 0.f;
#pragma unroll
    for (int nt = 0; nt < 4; ++nt) {
        float p = rmask[0] * C[nt][0] + rmask[1] * C[nt][1] + rmask[2] * C[nt][2] + rmask[3] * C[nt][3];
        p += __shfl_xor(p, 16);
        p += __shfl_xor(p, 32);
        if (quad == 0) red[wave * 576 + nt * 16 + colc] = p;
    }
#pragma unroll
    for (int rr = 0; rr < NR; ++rr) {
        float w0 = wsl[rr][rowl0], w1 = wsl[rr][rowl0 + 1];
        float w2 = wsl[rr][rowl0 + 2], w3 = wsl[rr][rowl0 + 3];
#pragma unroll
        for (int nt = 0; nt < 4; ++nt) {
            float p = w0 * C[nt][0] + w1 * C[nt][1] + w2 * C[nt][2] + w3 * C[nt][3];
            p += __shfl_xor(p, 16);
            p += __shfl_xor(p, 32);
            if (quad == 0) red[wave * 576 + 64 + rr * 64 + nt * 16 + colc] = p;
        }
    }
    __syncthreads();
    for (int j = tid; j < 1152; j += 256) {
        int rr = j >> 7, c = j & 127;          // rr==8 -> X1
        int u = c >> 6, cc = c & 63;
        int o = (rr < 8) ? (64 + rr * 64 + cc) : cc;
        S2P[(size_t)blockIdx.x * 1152 + j] = red[(u * 2) * 576 + o] + red[(u * 2 + 1) * 576 + o];
    }
}

// ---------------- reduce S2P[NB][1152] -> S2X1[1152] (atomic finish, 63 stripes of 25) ----------------
__global__ void s2red_k(const float* __restrict__ S2P, float* __restrict__ S2X1) {
    int cb = blockIdx.x % 5, stripe = blockIdx.x / 5;
    int c = cb * 256 + threadIdx.x;
    if (c >= 1152) return;
    int b0 = stripe * 25, b1 = min(NB, b0 + 25);
    if (b0 >= NB) return;
    float s0 = 0.f, s1 = 0.f;
    int b = b0;
    for (; b + 1 < b1; b += 2) {
        s0 += S2P[(size_t)b * 1152 + c];
        s1 += S2P[(size_t)(b + 1) * 1152 + c];
    }
    if (b < b1) s0 += S2P[(size_t)b * 1152 + c];
    atomicAdd(&S2X1[c], s0 + s1);
}

// ---------------- final: out = (S2.W2 + X1.root2)/N + b2  (1024 thr, 8-way split, 2 ILP chains) ----------------
__global__ __launch_bounds__(1024) void final_k(
    const float* __restrict__ S2X1, const float* __restrict__ W2,
    const float* __restrict__ root2, const float* __restrict__ b2, float* __restrict__ out)
{
    __shared__ float red[1024];
    const int o = threadIdx.x & 127, c = threadIdx.x >> 7;  // 8 chunks of 144 terms
    float s = 0.f, s2 = 0.f;
#pragma unroll 2
    for (int j = c * 144; j < (c + 1) * 144; j += 2) {
        float v0 = S2X1[j], v1 = S2X1[j + 1];
        float w0 = (j < 1024) ? W2[(size_t)j * DIM + o] : root2[(size_t)(j - 1024) * DIM + o];
        float w1 = (j + 1 < 1024) ? W2[(size_t)(j + 1) * DIM + o] : root2[(size_t)(j + 1 - 1024) * DIM + o];
        s += v0 * w0; s2 += v1 * w1;
    }
    red[threadIdx.x] = s + s2;
    __syncthreads();
    if (c == 0) {
        float tot = 0.f;
#pragma unroll
        for (int k = 0; k < 8; ++k) tot += red[o + 128 * k];
        out[o] = tot * (1.0f / NN) + b2[o];
    }
}

extern "C" void kernel_launch(void* const* d_in, const int* in_sizes, int n_in,
                              void* d_out, int out_size, void* d_ws, size_t ws_size,
                              hipStream_t stream)
{
    const int*   h     = (const int*)d_in[0];
    const int*   r     = (const int*)d_in[1];
    const int*   t     = (const int*)d_in[2];
    const float* x_emb = (const float*)d_in[3];
    const float* W1    = (const float*)d_in[4];
    const float* root1 = (const float*)d_in[5];
    const float* b1    = (const float*)d_in[6];
    const float* W2    = (const float*)d_in[7];
    const float* root2 = (const float*)d_in[8];
    const float* b2    = (const float*)d_in[9];

    float* ws     = (float*)d_ws;
    int*   cnt    = (int*)(ws + OFF_CNT);
    float* wsum   = ws + OFF_WSUM;
    float* S2     = ws + OFF_S2;      // 1024 S2 + 128 X1 contiguous
    int*   blkcnt = (int*)(ws + OFF_BCNT);
    int*   blkbuf = (int*)(ws + OFF_BBUF);
    __bf16* xb    = (__bf16*)(ws + OFF_XB);
    __bf16* wf    = (__bf16*)(ws + OFF_WF);
    float* S2P    = ws + OFF_S2P;

    // zero cnt + wsum + S2X1 + blkcnt (ws re-poisoned to 0xAA before every timed launch)
    hipMemsetAsync(ws, 0, (size_t)826160 * sizeof(float), stream);

    // merged cast + weight-frag + count + bucket-assign (one edge pass, term-major key)
    prep_k<<<1600, 256, 0, stream>>>(x_emb, xb, W1, root1, wf, h, r, t, cnt, blkcnt, blkbuf);

    // wsum: inv derived from cnt directly (no scan, no CSR)
    wsum_k<<<782, 256, 0, stream>>>(h, r, t, cnt, wsum);

    // fused layer 1 + layer-2 partials: stage-then-reduce, zero hot-path atomics
    rgcn_fused_k<<<NB, 256, 0, stream>>>(blkcnt, blkbuf, xb, wf, b1, wsum, S2P);

    s2red_k<<<315, 256, 0, stream>>>(S2P, S2);
    final_k<<<1, 1024, 0, stream>>>(S2, W2, root2, b2, (float*)d_out);
}